// Round 3
// baseline (232.905 us; speedup 1.0000x reference)
//
#include <hip/hip_runtime.h>

// Elementwise clamp: out = min(max(x, lo), hi)
// x: 33,554,432 fp32, clamp_params: [lo, hi] fp32.
// 256 MiB traffic -> ~43 us roofline at 6.3 TB/s achievable.
// Round 2 -> 3 probe: peak-BW copy shape — 8 float4s/thread (128 B/lane MLP),
// 4096 blocks, split-stream indexing (every VMEM op = fully-coalesced 1 KiB
// wave access), nontemporal retained. If this doesn't move dur_us, the
// kernel slice is BW-saturated and the remaining time is harness floor.

typedef float vf4 __attribute__((ext_vector_type(4)));

#define VPT 8  // float4s per thread

__global__ void __launch_bounds__(256) clamp_kernel(
    const vf4* __restrict__ x,
    const float* __restrict__ cp,
    vf4* __restrict__ out,
    int stride)       // total threads = n4 / VPT
{
    const float lo = cp[0];
    const float hi = cp[1];

    const int i = blockIdx.x * blockDim.x + threadIdx.x;

    vf4 v[VPT];
#pragma unroll
    for (int k = 0; k < VPT; ++k)
        v[k] = __builtin_nontemporal_load(&x[i + k * stride]);

#pragma unroll
    for (int k = 0; k < VPT; ++k) {
        v[k].x = fminf(fmaxf(v[k].x, lo), hi);
        v[k].y = fminf(fmaxf(v[k].y, lo), hi);
        v[k].z = fminf(fmaxf(v[k].z, lo), hi);
        v[k].w = fminf(fmaxf(v[k].w, lo), hi);
    }

#pragma unroll
    for (int k = 0; k < VPT; ++k)
        __builtin_nontemporal_store(v[k], &out[i + k * stride]);
}

extern "C" void kernel_launch(void* const* d_in, const int* in_sizes, int n_in,
                              void* d_out, int out_size, void* d_ws, size_t ws_size,
                              hipStream_t stream)
{
    const vf4*   x  = (const vf4*)d_in[0];
    const float* cp = (const float*)d_in[1];
    vf4* out = (vf4*)d_out;

    const int n  = in_sizes[0];     // 33,554,432 fp32 elements
    const int n4 = n / 4;           // 8,388,608 float4s (exact)
    const int threads = n4 / VPT;   // 1,048,576 threads (exact)

    const int block = 256;
    const int grid = threads / block;   // 4096 blocks

    clamp_kernel<<<grid, block, 0, stream>>>(x, cp, out, threads);
}

// Round 4
// 223.810 us; speedup vs baseline: 1.0406x; 1.0406x over previous
//
#include <hip/hip_runtime.h>

// Elementwise clamp: out = min(max(x, lo), hi)
// x: 33,554,432 fp32 (4194304 x 8), clamp_params: [lo, hi] fp32.
// Memory-bound stream: 256 MiB traffic, ~43 us roofline at 6.3 TB/s.
// Round 3 -> 4: revert to the R1 plateau shape (best measured): one float4
// per thread, 32,768 blocks. R2 (2x/thread, nontemporal) tied within noise;
// R3 (8x/thread, 4096 blocks) regressed ~9 us (scattered 8-way streams hurt
// DRAM locality). Simple dense 1:1 mapping saturates mixed read+write BW.

__global__ void __launch_bounds__(256) clamp_kernel(
    const float4* __restrict__ x,
    const float* __restrict__ cp,
    float4* __restrict__ out,
    int n4)
{
    const float lo = cp[0];
    const float hi = cp[1];
    int i = blockIdx.x * blockDim.x + threadIdx.x;
    if (i < n4) {
        float4 v = x[i];
        v.x = fminf(fmaxf(v.x, lo), hi);
        v.y = fminf(fmaxf(v.y, lo), hi);
        v.z = fminf(fmaxf(v.z, lo), hi);
        v.w = fminf(fmaxf(v.w, lo), hi);
        out[i] = v;
    }
}

extern "C" void kernel_launch(void* const* d_in, const int* in_sizes, int n_in,
                              void* d_out, int out_size, void* d_ws, size_t ws_size,
                              hipStream_t stream)
{
    const float4* x  = (const float4*)d_in[0];
    const float*  cp = (const float*)d_in[1];
    float4* out = (float4*)d_out;

    const int n  = in_sizes[0];   // 33,554,432 fp32 elements
    const int n4 = n / 4;         // 8,388,608 float4s (exact)

    const int block = 256;
    const int grid = (n4 + block - 1) / block;   // 32,768 blocks

    clamp_kernel<<<grid, block, 0, stream>>>(x, cp, out, n4);
}